// Round 13
// baseline (142.998 us; speedup 1.0000x reference)
//
#include <hip/hip_runtime.h>

namespace {
constexpr int N = 100000;
constexpr int E = 1600000;
constexpr int D = 128;
constexpr int U = 64;
constexpr int C = 40;
constexpr int C2 = C / 2;   // 20 packed bf16x2 words per row
constexpr int RP = 32;      // padded row stride in u32 (128 B)
constexpr int SLOTS = 64;   // padded CSR slots per node; deg ~ Poisson(16), P(>64) ~ 1e-15
constexpr int NB = (N + 255) / 256;  // 391 buckets of 256 nodes
constexpr int CAP = 4608;   // bucket capacity
constexpr int EPB = 16;
constexpr int TPB = 256;
constexpr int GK = 136;     // padded Gbf row stride in bf16 (272 B: 2-way bank alias = free)
constexpr int NT = (N + 15) / 16;    // 6250 16-row tiles
constexpr int PROJ_GRID = 782;       // 782 blocks * 4 waves * 2 tiles = 6256 >= NT

// workspace layout (element offsets; 4-byte units; all offsets 128B-aligned)
constexpr size_t OFF_BCUR = 0;                               // 512 ints
constexpr size_t OFF_META = OFF_BCUR + 512;                  // 2*N ints: {cnt, rdeg_bits}
constexpr size_t OFF_CSR = OFF_META + (size_t)2 * N;         // 2*N*SLOTS ints
constexpr size_t OFF_BBUF = OFF_CSR + (size_t)2 * N * SLOTS; // NB*CAP*2 ints (packed int2)
constexpr size_t BBUF_INTS = (size_t)NB * CAP * 2;
constexpr size_t OFF_P1 = OFF_BBUF + BBUF_INTS;              // N*C floats
constexpr size_t OFF_P2B = OFF_P1 + (size_t)N * C + 32;      // N*RP u32
constexpr size_t OFF_RBF = OFF_P2B + (size_t)N * RP;         // N*RP u32
constexpr size_t OFF_GBF = OFF_RBF + (size_t)N * RP;         // 128*GK u16 = 8704 u32
constexpr size_t OFF_BC = OFF_GBF + 128 * GK / 2;            // C floats
} // namespace

// ---- bf16 pack/unpack (RNE) ----
__device__ inline unsigned f2bf(float x) {
    unsigned u = __float_as_uint(x);
    return (u + 0x7fffu + ((u >> 16) & 1u)) >> 16;
}
__device__ inline unsigned pack_bf2(float a, float b) { return f2bf(a) | (f2bf(b) << 16); }
__device__ inline float2 unpack_bf2(unsigned v) {
    return make_float2(__uint_as_float(v << 16), __uint_as_float(v & 0xffff0000u));
}

typedef __attribute__((ext_vector_type(8))) short bf16x8;
typedef __attribute__((ext_vector_type(4))) float f32x4;

// ---- fold weights into one bf16 B^T matrix Gbf[n][k] (n=0..119 used, padded to 128):
//   n<40:  G0 = (W0-W2)@Wd ; n<80: G1 = -(W1@Wd) ; n<120: G2 = 2*(W2@Wd) ; else 0
// plus bc = b@Wd + bd (fp32). Block 0 also zeroes the bucket cursors.
__global__ void prep_weights(const float* __restrict__ W, const float* __restrict__ b,
                             const float* __restrict__ Wd, const float* __restrict__ bd,
                             unsigned short* __restrict__ Gbf, float* __restrict__ bc,
                             int* __restrict__ bcur) {
    if (blockIdx.x == 0) {
        for (int i = threadIdx.x; i < 512; i += 256) bcur[i] = 0;
    }
    int t = blockIdx.x * blockDim.x + threadIdx.x;
    if (t < 128 * 128) {
        int n = t >> 7, k = t & 127;
        float s = 0.f;
        if (n < 40) {
            const float* W0 = W + (size_t)k * U;
            const float* W2 = W + (size_t)2 * D * U + (size_t)k * U;
            for (int u = 0; u < U; ++u) s += (W0[u] - W2[u]) * Wd[u * C + n];
        } else if (n < 80) {
            const float* W1 = W + (size_t)D * U + (size_t)k * U;
            for (int u = 0; u < U; ++u) s -= W1[u] * Wd[u * C + (n - 40)];
        } else if (n < 120) {
            const float* W2 = W + (size_t)2 * D * U + (size_t)k * U;
            for (int u = 0; u < U; ++u) s += 2.f * W2[u] * Wd[u * C + (n - 80)];
        }
        Gbf[n * GK + k] = (unsigned short)f2bf(s);
    } else if (t < 128 * 128 + C) {
        int c = t - 128 * 128;
        float s = bd[c];
        for (int u = 0; u < U; ++u) s += b[u] * Wd[u * C + c];
        bc[c] = s;
    }
}

// Pass C: two-level counting scatter into per-bucket contiguous regions.
// Records packed to int2: w0 = src(24b) | dst_low8 << 24 ; w1 = ew bits.
__global__ __launch_bounds__(TPB) void bucket_scatter(const int* __restrict__ src,
                                                      const int* __restrict__ dst,
                                                      const float* __restrict__ ew,
                                                      int* __restrict__ bcur,
                                                      int2* __restrict__ bbuf2) {
    __shared__ int hist[NB];
    __shared__ int base[NB];
    int t = threadIdx.x;
    for (int i = t; i < NB; i += TPB) hist[i] = 0;
    __syncthreads();

    size_t e0 = (size_t)blockIdx.x * (TPB * EPB);
    int ms[EPB], md[EPB], mw[EPB], mr[EPB];
#pragma unroll
    for (int k = 0; k < EPB; ++k) {
        size_t e = e0 + (size_t)k * TPB + t;
        if (e < E) {
            ms[k] = src[e];
            md[k] = dst[e];
            mw[k] = __float_as_int(ew[e]);
            mr[k] = atomicAdd(&hist[md[k] >> 8], 1);
        } else {
            md[k] = -1;
        }
    }
    __syncthreads();
    for (int i = t; i < NB; i += TPB) {
        int c = hist[i];
        base[i] = c ? atomicAdd(&bcur[i], c) : 0;
    }
    __syncthreads();
#pragma unroll
    for (int k = 0; k < EPB; ++k) {
        if (md[k] >= 0) {
            int bkt = md[k] >> 8;
            int slot = base[bkt] + mr[k];
            if (slot < CAP)
                bbuf2[(size_t)bkt * CAP + slot] =
                    make_int2(ms[k] | ((md[k] & 255) << 24), mw[k]);
        }
    }
}

// Pass D: one block per bucket; LDS-only slotting + weighted degree. Small LDS
// (2KB) -> high occupancy to hide LDS-atomic latency. Zero-pads CSR rows to a
// multiple of 16 and writes meta[n] = {cnt, 1/max(deg,1e-12)}.
__global__ __launch_bounds__(256) void csr_build(const int* __restrict__ bcur,
                                                 const int2* __restrict__ bbuf2,
                                                 int2* __restrict__ meta,
                                                 int2* __restrict__ csr) {
    __shared__ int lcur[256];
    __shared__ float lw[256];
    int b = blockIdx.x;
    int t = threadIdx.x;
    lcur[t] = 0;
    lw[t] = 0.f;
    __syncthreads();
    int cnt = min(bcur[b], CAP);
    for (int i = t; i < cnt; i += 256) {
        int2 r = bbuf2[(size_t)b * CAP + i];
        int idx = ((unsigned)r.x) >> 24;
        int srcn = r.x & 0x00FFFFFF;
        int slot = atomicAdd(&lcur[idx], 1);
        atomicAdd(&lw[idx], __int_as_float(r.y));
        if (slot < SLOTS)
            csr[(((size_t)(b << 8) + idx) << 6) + slot] = make_int2(srcn, r.y);
    }
    __syncthreads();
    int node = (b << 8) + t;
    if (node < N) {
        int c = min(lcur[t], SLOTS);
        float rdeg = 1.f / fmaxf(lw[t], 1e-12f);
        meta[node] = make_int2(c, __float_as_int(rdeg));
        int padded = min((c + 15) & ~15, SLOTS);
        for (int s = c; s < padded; ++s)
            csr[((size_t)node << 6) + s] = make_int2(0, 0);
    }
}

// proj_mfma2: [N x 128] @ [128 x 120] bf16 MFMA GEMM, A direct-from-global.
// LDS holds only G (34.8 KB, staged once per block); each wave grid-strides
// over 16-row tiles. A-fragment load: lane l reads x[row16 + (l&15)]
// [ks*32 + (l>>4)*8 ...+8] = 2 float4 -> 8 bf16 (fully coalesced: per ks the
// wave covers 16 rows x one whole 128B line). No per-tile __syncthreads.
//   cols 0-39 -> out(+bc) fp32 ; 40-79 -> P1 fp32 ; 80-119 -> P2B bf16 u16
__global__ __launch_bounds__(256) void proj_mfma2(const float* __restrict__ X,
                                                  const uint4* __restrict__ Gu4,
                                                  const float* __restrict__ bc,
                                                  float* __restrict__ out,
                                                  float* __restrict__ P1,
                                                  unsigned short* __restrict__ P2B16) {
    __shared__ __align__(16) unsigned short g_s[128 * GK];  // 34.8 KB
    __shared__ float bc_s[C];
    int t = threadIdx.x;

    uint4* gs4 = (uint4*)g_s;
    for (int i = t; i < 128 * GK / 8; i += 256) gs4[i] = Gu4[i];
    if (t < C) bc_s[t] = bc[t];
    __syncthreads();

    int w = t >> 6, l = t & 63;
    int lr = l & 15, lh = l >> 4;

    for (int tile = blockIdx.x * 4 + w; tile < NT; tile += PROJ_GRID * 4) {
        int row0 = tile * 16;
        int r = min(row0 + lr, N - 1);
        const float4* xr = (const float4*)(X + (size_t)r * D);

        bf16x8 afr[4];
#pragma unroll
        for (int ks = 0; ks < 4; ++ks) {
            float4 v0 = xr[ks * 8 + lh * 2];
            float4 v1 = xr[ks * 8 + lh * 2 + 1];
            union { unsigned u[4]; bf16x8 v; } cv;
            cv.u[0] = pack_bf2(v0.x, v0.y);
            cv.u[1] = pack_bf2(v0.z, v0.w);
            cv.u[2] = pack_bf2(v1.x, v1.y);
            cv.u[3] = pack_bf2(v1.z, v1.w);
            afr[ks] = cv.v;
        }

        f32x4 acc[8];
#pragma unroll
        for (int tt = 0; tt < 8; ++tt) {
            acc[tt] = (f32x4){0.f, 0.f, 0.f, 0.f};
#pragma unroll
            for (int ks = 0; ks < 4; ++ks) {
                bf16x8 bfr = *(const bf16x8*)(g_s + (tt * 16 + lr) * GK + ks * 32 + lh * 8);
                acc[tt] = __builtin_amdgcn_mfma_f32_16x16x32_bf16(afr[ks], bfr, acc[tt], 0, 0, 0);
            }
        }

        // epilogue: C/D mapping col = tt*16 + (lane&15), row = (lane>>4)*4 + reg
#pragma unroll
        for (int tt = 0; tt < 8; ++tt) {
            int gcol = tt * 16 + lr;
#pragma unroll
            for (int rr = 0; rr < 4; ++rr) {
                size_t grow = (size_t)row0 + lh * 4 + rr;
                if (grow >= N) continue;
                float v = acc[tt][rr];
                if (gcol < 40) {
                    out[grow * C + gcol] = v + bc_s[gcol];
                } else if (gcol < 80) {
                    P1[grow * C + (gcol - 40)] = v;
                } else if (gcol < 120) {
                    P2B16[grow * 64 + (gcol - 80)] = (unsigned short)f2bf(v);
                }
            }
        }
    }
}

// gather SpMM v4: scalar metadata + precomputed rdeg + 16-edge batches.
//   Y[n] = Add[n] + rdeg * sum_e w_e * Xg[src_e]
// One wave/node. CSR rows zero-padded to multiple of 16 -> no tail masking.
// Lanes 0-31 handle edges j0..j0+7, lanes 32-63 handle j0+8..j0+15; combined
// via shfl_xor(32). OUT_BF writes the full 128B padded row -> no RMW.
template <bool OUT_BF>
__global__ __launch_bounds__(256) void spmm40v4(const int2* __restrict__ meta,
                                                const int2* __restrict__ csr,
                                                const unsigned* __restrict__ Xg,
                                                const float* __restrict__ Add,
                                                void* __restrict__ Yv) {
    int wid = (blockIdx.x * blockDim.x + threadIdx.x) >> 6;
    if (wid >= N) return;
    int uw = __builtin_amdgcn_readfirstlane(wid);
    int2 m = meta[uw];                     // uniform -> s_load_dwordx2
    int c = m.x;
    float rdeg = __int_as_float(m.y);
    const int2* __restrict__ row = csr + ((size_t)uw << 6);
    int lane = threadIdx.x & 63;
    bool hi = lane >= 32;
    unsigned voff = (unsigned)(lane & 31); // word index within padded 32-word row

    float2 ad = make_float2(0.f, 0.f);
    if (lane < C2) ad = ((const float2*)Add)[(size_t)wid * C2 + lane];

    float2 acc = make_float2(0.f, 0.f);
    for (int j0 = 0; j0 < c; j0 += 16) {
        unsigned va[8];
        float wa[8];
#pragma unroll
        for (int k = 0; k < 8; ++k) {
            int2 a = row[j0 + k];          // uniform -> s_load
            int2 b = row[j0 + 8 + k];
            int col = hi ? b.x : a.x;
            wa[k] = __int_as_float(hi ? b.y : a.y);
            va[k] = Xg[((unsigned)col << 5) + voff];  // SGPR base + 32-bit voffset
        }
#pragma unroll
        for (int k = 0; k < 8; ++k) {
            float2 v = unpack_bf2(va[k]);
            acc.x = fmaf(wa[k], v.x, acc.x);
            acc.y = fmaf(wa[k], v.y, acc.y);
        }
    }
    acc.x += __shfl_xor(acc.x, 32);
    acc.y += __shfl_xor(acc.y, 32);

    if (OUT_BF) {
        if (lane < 32) {
            unsigned o = 0u;
            if (lane < C2)
                o = pack_bf2(fmaf(acc.x, rdeg, ad.x), fmaf(acc.y, rdeg, ad.y));
            ((unsigned*)Yv)[((size_t)wid << 5) + lane] = o;  // full 128B row, no RMW
        }
    } else {
        if (lane < C2) {
            ((float2*)Yv)[(size_t)wid * C2 + lane] =
                make_float2(fmaf(acc.x, rdeg, ad.x), fmaf(acc.y, rdeg, ad.y));
        }
    }
}

extern "C" void kernel_launch(void* const* d_in, const int* in_sizes, int n_in,
                              void* d_out, int out_size, void* d_ws, size_t ws_size,
                              hipStream_t stream) {
    const float* x = (const float*)d_in[0];
    const int* ei = (const int*)d_in[1];   // (2, E): src = ei, dst = ei + E
    const float* ew = (const float*)d_in[2];
    const float* W = (const float*)d_in[3];
    const float* b = (const float*)d_in[4];
    const float* Wd = (const float*)d_in[5];
    const float* bd = (const float*)d_in[6];
    float* out = (float*)d_out;

    const int* src = ei;
    const int* dst = ei + E;

    float* ws = (float*)d_ws;
    int* bcur = (int*)(ws + OFF_BCUR);
    int2* meta = (int2*)(ws + OFF_META);
    int2* csr = (int2*)(ws + OFF_CSR);
    int2* bbuf2 = (int2*)(ws + OFF_BBUF);
    float* P1 = ws + OFF_P1;
    unsigned* P2B = (unsigned*)(ws + OFF_P2B);
    unsigned* Rbf = (unsigned*)(ws + OFF_RBF);
    unsigned short* Gbf = (unsigned short*)(ws + OFF_GBF);
    float* bc = ws + OFF_BC;

    // prep: fold weights + zero bucket cursors (no memset dispatch)
    prep_weights<<<(128 * 128 + C + 255) / 256, 256, 0, stream>>>(W, b, Wd, bd, Gbf, bc, bcur);

    // two-level counting sort, packed int2 records
    bucket_scatter<<<(E + TPB * EPB - 1) / (TPB * EPB), TPB, 0, stream>>>(src, dst, ew, bcur, bbuf2);
    csr_build<<<NB, 256, 0, stream>>>(bcur, bbuf2, meta, csr);

    // MFMA GEMM: out = x@G0 + bc ; P1 = x@G1 ; P2B = bf16(x@G2)
    proj_mfma2<<<PROJ_GRID, 256, 0, stream>>>(x, (const uint4*)Gbf, bc, out, P1,
                                              (unsigned short*)P2B);

    // Rbf = bf16(P1 + A_hat @ P2)
    spmm40v4<true><<<((size_t)N * 64 + 255) / 256, 256, 0, stream>>>(meta, csr, P2B, P1, Rbf);
    // out += A_hat @ R
    spmm40v4<false><<<((size_t)N * 64 + 255) / 256, 256, 0, stream>>>(meta, csr, Rbf, out, out);
}